// Round 2
// baseline (1244.300 us; speedup 1.0000x reference)
//
#include <hip/hip_runtime.h>

#define HIDDEN 32
#define SORTK 30
#define SP_CAP 3072
#define BSH 7                 // bucket shift: 128 nodes per bucket
#define BNODES (1 << BSH)
#define BCAP 2048             // LDS capacity per bucket (mean ~1280, sd ~36)

static inline int ceil_div_i(long long a, int b){ return (int)((a + b - 1) / b); }

// ---------------- degree / dis ----------------
__global__ void count_kernel(const int* __restrict__ dsts, int* __restrict__ degcnt, int E){
  int e = blockIdx.x * blockDim.x + threadIdx.x;
  if (e < E) atomicAdd(&degcnt[dsts[e]], 1);
}

__global__ void dis_kernel(const int* __restrict__ degcnt, float* __restrict__ dis, int N){
  int n = blockIdx.x * blockDim.x + threadIdx.x;
  if (n < N){
    float d = (float)degcnt[n] + 1.0f;
    dis[n] = __fdiv_rn(1.0f, __fsqrt_rn(d));   // IEEE: matches 1/np.sqrt
  }
}

// ---------------- exclusive scan (3-kernel hierarchical) ----------------
__global__ void scanA(const int* __restrict__ in, int* __restrict__ bsum, int n){
  int i = blockIdx.x * 256 + threadIdx.x;
  int v = (i < n) ? in[i] : 0;
  for (int o = 32; o; o >>= 1) v += __shfl_down(v, o, 64);
  __shared__ int ws[4];
  int lane = threadIdx.x & 63, wid = threadIdx.x >> 6;
  if (lane == 0) ws[wid] = v;
  __syncthreads();
  if (threadIdx.x == 0) bsum[blockIdx.x] = ws[0] + ws[1] + ws[2] + ws[3];
}

// single block, 1024 threads; requires nb <= 1024 (nb = ceil(250000/256) = 977)
__global__ void scanB(int* __restrict__ bsum, int nb, int* __restrict__ offsets, int N){
  int tid = threadIdx.x;
  int v = (tid < nb) ? bsum[tid] : 0;
  int x = v;
  int lane = tid & 63, wid = tid >> 6;
  for (int o = 1; o < 64; o <<= 1){ int y = __shfl_up(x, o, 64); if (lane >= o) x += y; }
  __shared__ int wsum[16]; __shared__ int woff[16]; __shared__ int tot;
  if (lane == 63) wsum[wid] = x;
  __syncthreads();
  if (tid == 0){ int run = 0; for (int w = 0; w < 16; w++){ woff[w] = run; run += wsum[w]; } tot = run; }
  __syncthreads();
  if (tid < nb) bsum[tid] = x - v + woff[wid];
  if (tid == 0) offsets[N] = tot;   // = E
}

__global__ void scanC(const int* __restrict__ in, const int* __restrict__ boff,
                      int* __restrict__ offsets, int n){
  int i = blockIdx.x * 256 + threadIdx.x;
  int v = (i < n) ? in[i] : 0;
  int x = v;
  int lane = threadIdx.x & 63, wid = threadIdx.x >> 6;
  for (int o = 1; o < 64; o <<= 1){ int y = __shfl_up(x, o, 64); if (lane >= o) x += y; }
  __shared__ int wsum[4]; __shared__ int woff[4];
  if (lane == 63) wsum[wid] = x;
  __syncthreads();
  if (threadIdx.x == 0){ int run = 0; for (int w = 0; w < 4; w++){ woff[w] = run; run += wsum[w]; } }
  __syncthreads();
  if (i < n) offsets[i] = x - v + woff[wid] + boff[blockIdx.x];
}

// ---------------- bucketed CSR build ----------------
// bcur[b] = offsets[min(b*128, N)] (buckets are node-aligned => regions exact)
__global__ void init_bcur(const int* __restrict__ offsets, int* __restrict__ bcur,
                          int NB, int N){
  int b = blockIdx.x * blockDim.x + threadIdx.x;
  if (b < NB){
    int n = b << BSH; if (n > N) n = N;
    bcur[b] = offsets[n];
  }
}

// append packed key (local_dst<<22)|eid into bucket region (dense appends => full lines)
__global__ void bucket_scatter(const int* __restrict__ dsts, int* __restrict__ bcur,
                               int* __restrict__ staging, int E){
  int e = blockIdx.x * blockDim.x + threadIdx.x;
  if (e < E){
    int d = dsts[e];
    int slot = atomicAdd(&bcur[d >> BSH], 1);
    staging[slot] = ((d & (BNODES - 1)) << 22) | e;
  }
}

// one block per bucket: LDS stable sort by (dst, eid), then coalesced csr write of srcs
__global__ __launch_bounds__(BNODES) void bucket_sort_kernel(
    const int* __restrict__ offsets, const int* __restrict__ staging,
    const int* __restrict__ srcs, int* __restrict__ csr, int N){
  __shared__ int ebuf[BCAP];
  __shared__ int obuf[BCAP];
  int b = blockIdx.x, t = threadIdx.x;
  int n0 = b << BSH;
  int n1 = n0 + BNODES; if (n1 > N) n1 = N;
  int gbeg = offsets[n0], gend = offsets[n1];
  int cnt = gend - gbeg;

  if (cnt <= BCAP){
    for (int i = t; i < cnt; i += BNODES) ebuf[i] = staging[gbeg + i];
    __syncthreads();
    int n = n0 + t;
    if (n < n1){
      int ls = offsets[n] - gbeg;
      int m = 0;
      for (int i = 0; i < cnt; i++){
        int k = ebuf[i];                 // same addr across lanes => LDS broadcast
        if ((k >> 22) == t){
          int j = ls + m - 1;            // insertion by eid (low bits; same high bits)
          while (j >= ls && obuf[j] > k){ obuf[j + 1] = obuf[j]; j--; }
          obuf[j + 1] = k;
          m++;
        }
      }
    }
    __syncthreads();
    for (int i = t; i < cnt; i += BNODES)
      csr[gbeg + i] = srcs[obuf[i] & 0x3FFFFF];
  } else {
    // statistically unreachable fallback (correct, slow)
    int n = n0 + t;
    if (n < n1){
      int os = offsets[n], oe = offsets[n + 1];
      int prev = -1;
      for (int o = os; o < oe; o++){
        int best = 0x7fffffff;
        for (int i = gbeg; i < gend; i++){
          int k = staging[i];
          if ((k >> 22) == t){
            int eid = k & 0x3FFFFF;
            if (eid > prev && eid < best) best = eid;
          }
        }
        csr[o] = srcs[best]; prev = best;
      }
    }
  }
}

// ---------------- per-node matmul h = x @ W ----------------
template<int K>
__global__ void node_matmul(const float* __restrict__ xin, const float* __restrict__ W,
                            float* __restrict__ H, int N){
  __shared__ float Ws[K * 32];
  for (int i = threadIdx.x; i < K * 32; i += blockDim.x) Ws[i] = W[i];
  __syncthreads();
  int tid = blockIdx.x * blockDim.x + threadIdx.x;
  int n = tid >> 5, c = tid & 31;
  if (n >= N) return;
  const float* xr = xin + (size_t)n * K;
  float acc = 0.f;
  #pragma unroll
  for (int k = 0; k < K; k++) acc = fmaf(xr[k], Ws[k * 32 + c], acc);
  H[(size_t)n * 32 + c] = acc;
}

// ---------------- GCN aggregation (deterministic edge order, 4x pipelined) ----------
__global__ void agg_kernel(const float* __restrict__ H, const int* __restrict__ offsets,
                           const int* __restrict__ csr, const float* __restrict__ dis,
                           const float* __restrict__ bias, float* __restrict__ A, int N){
  int tid = blockIdx.x * blockDim.x + threadIdx.x;
  int n = tid >> 5, c = tid & 31;
  if (n >= N) return;
  float dn = dis[n];
  int s = offsets[n], e = offsets[n + 1];
  float acc = 0.f;
  int i = s;
  for (; i + 4 <= e; i += 4){
    int s0 = csr[i], s1 = csr[i+1], s2 = csr[i+2], s3 = csr[i+3];
    float h0 = H[(size_t)s0*32+c], h1 = H[(size_t)s1*32+c];
    float h2 = H[(size_t)s2*32+c], h3 = H[(size_t)s3*32+c];
    float w0 = __fmul_rn(dis[s0], dn), w1 = __fmul_rn(dis[s1], dn);
    float w2 = __fmul_rn(dis[s2], dn), w3 = __fmul_rn(dis[s3], dn);
    acc = __fadd_rn(acc, __fmul_rn(h0, w0));   // exact reference order preserved
    acc = __fadd_rn(acc, __fmul_rn(h1, w1));
    acc = __fadd_rn(acc, __fmul_rn(h2, w2));
    acc = __fadd_rn(acc, __fmul_rn(h3, w3));
  }
  for (; i < e; i++){
    int sr = csr[i];
    float w = __fmul_rn(dis[sr], dn);
    acc = __fadd_rn(acc, __fmul_rn(H[(size_t)sr * 32 + c], w));
  }
  float selfw = __fmul_rn(dn, dn);
  float v = __fadd_rn(acc, __fmul_rn(H[(size_t)n * 32 + c], selfw));
  v = __fadd_rn(v, bias[c]);
  A[(size_t)n * 32 + c] = fmaxf(v, 0.f);
}

// ---------------- graph boundaries (batch is sorted) ----------------
__global__ void gstarts_kernel(const int* __restrict__ batch, int* __restrict__ gstarts,
                               int N, int G){
  int g = blockIdx.x * blockDim.x + threadIdx.x;
  if (g > G) return;
  int lo = 0, hi = N;
  while (lo < hi){ int mid = (lo + hi) >> 1; if (batch[mid] < g) lo = mid + 1; else hi = mid; }
  gstarts[g] = lo;
}

// ---------------- sort-pool: stable top-30 by key desc, tie by index asc ----------------
__global__ void sort_pool_kernel(const float* __restrict__ A, const int* __restrict__ gstarts,
                                 float* __restrict__ pooled){
  int g = blockIdx.x;
  int s = gstarts[g], e = gstarts[g + 1];
  int c = e - s;
  __shared__ float keys[SP_CAP];
  bool uselds = (c <= SP_CAP);
  if (uselds){
    for (int i = threadIdx.x; i < c; i += blockDim.x) keys[i] = A[(size_t)(s + i) * 32 + 31];
  }
  __syncthreads();
  for (int i = threadIdx.x; i < c; i += blockDim.x){
    float ki = uselds ? keys[i] : A[(size_t)(s + i) * 32 + 31];
    int rank = 0; bool sel = true;
    for (int j = 0; j < c; j++){
      float kj = uselds ? keys[j] : A[(size_t)(s + j) * 32 + 31];
      if (kj > ki || (kj == ki && j < i)){
        if (++rank >= SORTK){ sel = false; break; }
      }
    }
    if (sel){
      for (int ch = 0; ch < 32; ch++)
        pooled[(size_t)g * 32 * SORTK + ch * SORTK + rank] = A[(size_t)(s + i) * 32 + ch];
    }
  }
}

// ---------------- head: conv1 -> conv2 -> dense1 -> dense2, one block per graph ----------
__global__ __launch_bounds__(128) void head_kernel(
    const float* __restrict__ pooled,
    const float* __restrict__ cw1, const float* __restrict__ cb1,
    const float* __restrict__ cw2, const float* __restrict__ cb2,
    const float* __restrict__ lw1, const float* __restrict__ lb1,
    const float* __restrict__ lw2, const float* __restrict__ lb2,
    float* __restrict__ out){
  int g = blockIdx.x;
  int t = threadIdx.x;
  __shared__ float sin_[32 * 30];
  __shared__ float c1[16 * 26];
  __shared__ float c2[32 * 22];
  __shared__ float d1[128];
  __shared__ float w1s[16 * 32 * 5];
  __shared__ float w2s[32 * 16 * 5];

  for (int i = t; i < 960; i += 128)  sin_[i] = pooled[(size_t)g * 960 + i];
  for (int i = t; i < 2560; i += 128) w1s[i] = cw1[i];
  for (int i = t; i < 2560; i += 128) w2s[i] = cw2[i];
  __syncthreads();

  for (int q = t; q < 16 * 26; q += 128){
    int o = q / 26, tt = q % 26;
    float acc = cb1[o];
    const float* wo = &w1s[o * 160];
    for (int i = 0; i < 32; i++){
      const float* si = &sin_[i * 30 + tt];
      #pragma unroll
      for (int k = 0; k < 5; k++) acc = fmaf(si[k], wo[i * 5 + k], acc);
    }
    c1[q] = fmaxf(acc, 0.f);
  }
  __syncthreads();

  for (int q = t; q < 32 * 22; q += 128){
    int o = q / 22, tt = q % 22;
    float acc = cb2[o];
    const float* wo = &w2s[o * 80];
    for (int i = 0; i < 16; i++){
      const float* si = &c1[i * 26 + tt];
      #pragma unroll
      for (int k = 0; k < 5; k++) acc = fmaf(si[k], wo[i * 5 + k], acc);
    }
    c2[q] = fmaxf(acc, 0.f);
  }
  __syncthreads();

  {
    float acc = lb1[t];
    for (int j = 0; j < 704; j++) acc = fmaf(c2[j], lw1[(size_t)j * 128 + t], acc);
    d1[t] = fmaxf(acc, 0.f);
  }
  __syncthreads();

  if (t == 0){
    float acc = lb2[0];
    for (int o = 0; o < 128; o++) acc = fmaf(d1[o], lw2[o], acc);
    out[g] = acc;
  }
}

// ---------------- launch ----------------
extern "C" void kernel_launch(void* const* d_in, const int* in_sizes, int n_in,
                              void* d_out, int out_size, void* d_ws, size_t ws_size,
                              hipStream_t stream){
  const float* x     = (const float*)d_in[0];
  const int*   ei    = (const int*)  d_in[1];
  const int*   batch = (const int*)  d_in[2];
  const float* W1  = (const float*)d_in[4];
  const float* b1  = (const float*)d_in[5];
  const float* W2  = (const float*)d_in[6];
  const float* b2  = (const float*)d_in[7];
  const float* W3  = (const float*)d_in[8];
  const float* b3  = (const float*)d_in[9];
  const float* cw1 = (const float*)d_in[10];
  const float* cb1 = (const float*)d_in[11];
  const float* cw2 = (const float*)d_in[12];
  const float* cb2 = (const float*)d_in[13];
  const float* lw1 = (const float*)d_in[14];
  const float* lb1 = (const float*)d_in[15];
  const float* lw2 = (const float*)d_in[16];
  const float* lb2 = (const float*)d_in[17];

  int N = in_sizes[0] / 9;
  int E = in_sizes[1] / 2;
  int G = out_size;
  const int* srcs = ei;
  const int* dsts = ei + E;
  int NB = ceil_div_i(N, BNODES);

  char* base = (char*)d_ws;
  size_t off = 0;
  auto alloc = [&](size_t bytes) -> void* {
    off = (off + 255) & ~(size_t)255;
    void* r = base + off; off += bytes; return r;
  };
  float* dis    = (float*)alloc((size_t)N * 4);
  float* H      = (float*)alloc((size_t)N * 32 * 4);
  float* A      = (float*)alloc((size_t)N * 32 * 4);
  float* pooled = (float*)alloc((size_t)G * 32 * SORTK * 4);
  int*   degcnt = (int*)alloc((size_t)N * 4);
  int*   offs   = (int*)alloc((size_t)(N + 1) * 4);
  int*   csr    = (int*)alloc((size_t)E * 4);
  int*   bsum   = (int*)alloc((size_t)ceil_div_i(N, 256) * 4);
  int*   gst    = (int*)alloc((size_t)(G + 1) * 4);
  int*   bcur   = (int*)alloc((size_t)NB * 4);
  int*   staging = (int*)H;   // alias: H is written only after CSR build completes
  (void)ws_size; (void)n_in;

  hipMemsetAsync(degcnt, 0, (size_t)N * 4, stream);
  hipMemsetAsync(pooled, 0, (size_t)G * 32 * SORTK * 4, stream);

  int nb = ceil_div_i(N, 256);
  count_kernel<<<ceil_div_i(E, 256), 256, 0, stream>>>(dsts, degcnt, E);
  dis_kernel<<<nb, 256, 0, stream>>>(degcnt, dis, N);
  scanA<<<nb, 256, 0, stream>>>(degcnt, bsum, N);
  scanB<<<1, 1024, 0, stream>>>(bsum, nb, offs, N);
  scanC<<<nb, 256, 0, stream>>>(degcnt, bsum, offs, N);
  init_bcur<<<ceil_div_i(NB, 256), 256, 0, stream>>>(offs, bcur, NB, N);
  bucket_scatter<<<ceil_div_i(E, 256), 256, 0, stream>>>(dsts, bcur, staging, E);
  bucket_sort_kernel<<<NB, BNODES, 0, stream>>>(offs, staging, srcs, csr, N);

  int nt = ceil_div_i((long long)N * 32, 256);
  node_matmul<9><<<nt, 256, 0, stream>>>(x, W1, H, N);
  agg_kernel<<<nt, 256, 0, stream>>>(H, offs, csr, dis, b1, A, N);
  node_matmul<32><<<nt, 256, 0, stream>>>(A, W2, H, N);
  agg_kernel<<<nt, 256, 0, stream>>>(H, offs, csr, dis, b2, A, N);
  node_matmul<32><<<nt, 256, 0, stream>>>(A, W3, H, N);
  agg_kernel<<<nt, 256, 0, stream>>>(H, offs, csr, dis, b3, A, N);

  gstarts_kernel<<<ceil_div_i(G + 1, 256), 256, 0, stream>>>(batch, gst, N, G);
  sort_pool_kernel<<<G, 128, 0, stream>>>(A, gst, pooled);
  head_kernel<<<G, 128, 0, stream>>>(pooled, cw1, cb1, cw2, cb2, lw1, lb1, lw2, lb2,
                                     (float*)d_out);
}

// Round 3
// 933.719 us; speedup vs baseline: 1.3326x; 1.3326x over previous
//
#include <hip/hip_runtime.h>

#define HIDDEN 32
#define SORTK 30
#define SP_CAP 3072
#define BSH 7                 // 128 nodes per bucket
#define BNODES (1 << BSH)
#define BCAP 2048             // LDS staging per bucket (mean ~1280, sd ~36)
#define HMAX 2048             // max buckets supported (N <= 262144)
#define NSEG 64               // scatter segments

static inline int ceil_div_i(long long a, int b){ return (int)((a + b - 1) / b); }

// ---------------- phase 1: per-segment LDS histogram ----------------
__global__ __launch_bounds__(256) void hist_kernel(const int* __restrict__ dsts,
                                                   int* __restrict__ hist,
                                                   int E, int NB, int segsz){
  __shared__ int h[HMAX];
  for (int i = threadIdx.x; i < NB; i += 256) h[i] = 0;
  __syncthreads();
  int seg = blockIdx.x;
  int e0 = seg * segsz;
  int e1 = e0 + segsz; if (e1 > E) e1 = E;
  for (int e = e0 + threadIdx.x; e < e1; e += 256)
    atomicAdd(&h[dsts[e] >> BSH], 1);
  __syncthreads();
  for (int i = threadIdx.x; i < NB; i += 256) hist[seg * NB + i] = h[i];
}

// ---------------- phase 2: per-bucket seg-prefix + bucket-base scan (1 block) ----------
__global__ __launch_bounds__(1024) void segscan_kernel(const int* __restrict__ hist,
                                                       int* __restrict__ segoff,
                                                       int* __restrict__ bbase,
                                                       int NB, int S){
  int t = threadIdx.x;
  int b0 = t * 2, b1 = t * 2 + 1;
  int tot0 = 0, tot1 = 0;
  if (b0 < NB){ int run = 0; for (int s = 0; s < S; s++){ int v = hist[s * NB + b0]; segoff[s * NB + b0] = run; run += v; } tot0 = run; }
  if (b1 < NB){ int run = 0; for (int s = 0; s < S; s++){ int v = hist[s * NB + b1]; segoff[s * NB + b1] = run; run += v; } tot1 = run; }
  int pair = tot0 + tot1;
  int lane = t & 63, wid = t >> 6;
  int x = pair;
  for (int o = 1; o < 64; o <<= 1){ int y = __shfl_up(x, o, 64); if (lane >= o) x += y; }
  __shared__ int wsum[16]; __shared__ int woff[16];
  if (lane == 63) wsum[wid] = x;
  __syncthreads();
  if (t == 0){ int run = 0; for (int w = 0; w < 16; w++){ woff[w] = run; run += wsum[w]; } }
  __syncthreads();
  int excl = x - pair + woff[wid];
  if (b0 < NB) bbase[b0] = excl;
  if (b1 < NB) bbase[b1] = excl + tot0;
}

// ---------------- phase 3: scatter with block-private regions (LDS atomics only) ------
__global__ __launch_bounds__(256) void scatter_kernel(const int* __restrict__ dsts,
                                                      const int* __restrict__ segoff,
                                                      const int* __restrict__ bbase,
                                                      int* __restrict__ staging,
                                                      int E, int NB, int segsz){
  __shared__ int cur[HMAX];
  int seg = blockIdx.x;
  for (int i = threadIdx.x; i < NB; i += 256) cur[i] = segoff[seg * NB + i] + bbase[i];
  __syncthreads();
  int e0 = seg * segsz;
  int e1 = e0 + segsz; if (e1 > E) e1 = E;
  for (int e = e0 + threadIdx.x; e < e1; e += 256){
    int d = dsts[e];
    int slot = atomicAdd(&cur[d >> BSH], 1);
    staging[slot] = ((d & (BNODES - 1)) << 22) | e;
  }
}

// ---------------- phase 4: per-bucket LDS sort by (dst,eid) + degcnt + dis + CSR ------
__global__ __launch_bounds__(BNODES) void bucket_sort_kernel(
    const int* __restrict__ bbase, const int* __restrict__ staging,
    const int* __restrict__ srcs, int* __restrict__ csr,
    int* __restrict__ degcnt, float* __restrict__ dis, int N, int NB, int E){
  __shared__ int ebuf[BCAP];
  __shared__ int obuf[BCAP];
  __shared__ int cnt[BNODES];
  __shared__ int w0tot;
  int b = blockIdx.x, t = threadIdx.x;
  int n0 = b << BSH;
  int n1 = n0 + BNODES; if (n1 > N) n1 = N;
  int gbeg = bbase[b];
  int gend = (b + 1 < NB) ? bbase[b + 1] : E;
  int cnt_all = gend - gbeg;
  cnt[t] = 0;
  __syncthreads();

  if (cnt_all <= BCAP){
    for (int i = t; i < cnt_all; i += BNODES){
      int k = staging[gbeg + i];
      ebuf[i] = k;
      atomicAdd(&cnt[k >> 22], 1);
    }
    __syncthreads();
    int v = cnt[t];
    int lane = t & 63, wid = t >> 6;
    int x = v;
    for (int o = 1; o < 64; o <<= 1){ int y = __shfl_up(x, o, 64); if (lane >= o) x += y; }
    if (wid == 0 && lane == 63) w0tot = x;
    __syncthreads();
    int ls = x - v + (wid ? w0tot : 0);   // local exclusive start
    int n = n0 + t;
    if (n < n1){
      degcnt[n] = v;
      float dd = (float)v + 1.0f;
      dis[n] = __fdiv_rn(1.0f, __fsqrt_rn(dd));
      int m = 0;
      for (int i = 0; i < cnt_all; i++){
        int k = ebuf[i];                 // broadcast read
        if ((k >> 22) == t){
          int j = ls + m - 1;            // insertion by eid
          while (j >= ls && obuf[j] > k){ obuf[j + 1] = obuf[j]; j--; }
          obuf[j + 1] = k;
          m++;
        }
      }
    }
    __syncthreads();
    for (int i = t; i < cnt_all; i += BNODES)
      csr[gbeg + i] = srcs[obuf[i] & 0x3FFFFF];
  } else {
    // statistically unreachable fallback (correct, slow)
    int n = n0 + t;
    int deg = 0;
    if (n < n1){
      for (int i = gbeg; i < gend; i++) if ((staging[i] >> 22) == t) deg++;
      degcnt[n] = deg;
      float dd = (float)deg + 1.0f;
      dis[n] = __fdiv_rn(1.0f, __fsqrt_rn(dd));
    }
    cnt[t] = deg;
    __syncthreads();
    if (n < n1){
      int ls = gbeg; for (int q = 0; q < t; q++) ls += cnt[q];
      int prev = -1;
      for (int o = 0; o < deg; o++){
        int best = 0x7fffffff;
        for (int i = gbeg; i < gend; i++){
          int k = staging[i];
          if ((k >> 22) == t){
            int eid = k & 0x3FFFFF;
            if (eid > prev && eid < best) best = eid;
          }
        }
        csr[ls + o] = srcs[best]; prev = best;
      }
    }
  }
}

// ---------------- exclusive scan (3-kernel hierarchical) ----------------
__global__ void scanA(const int* __restrict__ in, int* __restrict__ bsum, int n){
  int i = blockIdx.x * 256 + threadIdx.x;
  int v = (i < n) ? in[i] : 0;
  for (int o = 32; o; o >>= 1) v += __shfl_down(v, o, 64);
  __shared__ int ws[4];
  int lane = threadIdx.x & 63, wid = threadIdx.x >> 6;
  if (lane == 0) ws[wid] = v;
  __syncthreads();
  if (threadIdx.x == 0) bsum[blockIdx.x] = ws[0] + ws[1] + ws[2] + ws[3];
}

__global__ void scanB(int* __restrict__ bsum, int nb, int* __restrict__ offsets, int N){
  int tid = threadIdx.x;
  int v = (tid < nb) ? bsum[tid] : 0;
  int x = v;
  int lane = tid & 63, wid = tid >> 6;
  for (int o = 1; o < 64; o <<= 1){ int y = __shfl_up(x, o, 64); if (lane >= o) x += y; }
  __shared__ int wsum[16]; __shared__ int woff[16]; __shared__ int tot;
  if (lane == 63) wsum[wid] = x;
  __syncthreads();
  if (tid == 0){ int run = 0; for (int w = 0; w < 16; w++){ woff[w] = run; run += wsum[w]; } tot = run; }
  __syncthreads();
  if (tid < nb) bsum[tid] = x - v + woff[wid];
  if (tid == 0) offsets[N] = tot;   // = E
}

__global__ void scanC(const int* __restrict__ in, const int* __restrict__ boff,
                      int* __restrict__ offsets, int n){
  int i = blockIdx.x * 256 + threadIdx.x;
  int v = (i < n) ? in[i] : 0;
  int x = v;
  int lane = threadIdx.x & 63, wid = threadIdx.x >> 6;
  for (int o = 1; o < 64; o <<= 1){ int y = __shfl_up(x, o, 64); if (lane >= o) x += y; }
  __shared__ int wsum[4]; __shared__ int woff[4];
  if (lane == 63) wsum[wid] = x;
  __syncthreads();
  if (threadIdx.x == 0){ int run = 0; for (int w = 0; w < 4; w++){ woff[w] = run; run += wsum[w]; } }
  __syncthreads();
  if (i < n) offsets[i] = x - v + woff[wid] + boff[blockIdx.x];
}

// ---------------- per-node matmul h = x @ W ----------------
template<int K>
__global__ void node_matmul(const float* __restrict__ xin, const float* __restrict__ W,
                            float* __restrict__ H, int N){
  __shared__ float Ws[K * 32];
  for (int i = threadIdx.x; i < K * 32; i += blockDim.x) Ws[i] = W[i];
  __syncthreads();
  int tid = blockIdx.x * blockDim.x + threadIdx.x;
  int n = tid >> 5, c = tid & 31;
  if (n >= N) return;
  const float* xr = xin + (size_t)n * K;
  float acc = 0.f;
  #pragma unroll
  for (int k = 0; k < K; k++) acc = fmaf(xr[k], Ws[k * 32 + c], acc);
  H[(size_t)n * 32 + c] = acc;
}

// ---------------- GCN aggregation (deterministic edge order, 4x pipelined) ----------
__global__ void agg_kernel(const float* __restrict__ H, const int* __restrict__ offsets,
                           const int* __restrict__ csr, const float* __restrict__ dis,
                           const float* __restrict__ bias, float* __restrict__ A, int N){
  int tid = blockIdx.x * blockDim.x + threadIdx.x;
  int n = tid >> 5, c = tid & 31;
  if (n >= N) return;
  float dn = dis[n];
  int s = offsets[n], e = offsets[n + 1];
  float acc = 0.f;
  int i = s;
  for (; i + 4 <= e; i += 4){
    int s0 = csr[i], s1 = csr[i+1], s2 = csr[i+2], s3 = csr[i+3];
    float h0 = H[(size_t)s0*32+c], h1 = H[(size_t)s1*32+c];
    float h2 = H[(size_t)s2*32+c], h3 = H[(size_t)s3*32+c];
    float w0 = __fmul_rn(dis[s0], dn), w1 = __fmul_rn(dis[s1], dn);
    float w2 = __fmul_rn(dis[s2], dn), w3 = __fmul_rn(dis[s3], dn);
    acc = __fadd_rn(acc, __fmul_rn(h0, w0));   // exact reference order preserved
    acc = __fadd_rn(acc, __fmul_rn(h1, w1));
    acc = __fadd_rn(acc, __fmul_rn(h2, w2));
    acc = __fadd_rn(acc, __fmul_rn(h3, w3));
  }
  for (; i < e; i++){
    int sr = csr[i];
    float w = __fmul_rn(dis[sr], dn);
    acc = __fadd_rn(acc, __fmul_rn(H[(size_t)sr * 32 + c], w));
  }
  float selfw = __fmul_rn(dn, dn);
  float v = __fadd_rn(acc, __fmul_rn(H[(size_t)n * 32 + c], selfw));
  v = __fadd_rn(v, bias[c]);
  A[(size_t)n * 32 + c] = fmaxf(v, 0.f);
}

// ---------------- graph boundaries (batch is sorted) ----------------
__global__ void gstarts_kernel(const int* __restrict__ batch, int* __restrict__ gstarts,
                               int N, int G){
  int g = blockIdx.x * blockDim.x + threadIdx.x;
  if (g > G) return;
  int lo = 0, hi = N;
  while (lo < hi){ int mid = (lo + hi) >> 1; if (batch[mid] < g) lo = mid + 1; else hi = mid; }
  gstarts[g] = lo;
}

// ---------------- sort-pool: stable top-30 by key desc, tie by index asc ----------------
__global__ void sort_pool_kernel(const float* __restrict__ A, const int* __restrict__ gstarts,
                                 float* __restrict__ pooled){
  int g = blockIdx.x;
  int s = gstarts[g], e = gstarts[g + 1];
  int c = e - s;
  __shared__ float keys[SP_CAP];
  bool uselds = (c <= SP_CAP);
  if (uselds){
    for (int i = threadIdx.x; i < c; i += blockDim.x) keys[i] = A[(size_t)(s + i) * 32 + 31];
  }
  __syncthreads();
  for (int i = threadIdx.x; i < c; i += blockDim.x){
    float ki = uselds ? keys[i] : A[(size_t)(s + i) * 32 + 31];
    int rank = 0; bool sel = true;
    for (int j = 0; j < c; j++){
      float kj = uselds ? keys[j] : A[(size_t)(s + j) * 32 + 31];
      if (kj > ki || (kj == ki && j < i)){
        if (++rank >= SORTK){ sel = false; break; }
      }
    }
    if (sel){
      for (int ch = 0; ch < 32; ch++)
        pooled[(size_t)g * 32 * SORTK + ch * SORTK + rank] = A[(size_t)(s + i) * 32 + ch];
    }
  }
}

// ---------------- head: conv1 -> conv2 -> dense1 -> dense2, one block per graph ----------
__global__ __launch_bounds__(128) void head_kernel(
    const float* __restrict__ pooled,
    const float* __restrict__ cw1, const float* __restrict__ cb1,
    const float* __restrict__ cw2, const float* __restrict__ cb2,
    const float* __restrict__ lw1, const float* __restrict__ lb1,
    const float* __restrict__ lw2, const float* __restrict__ lb2,
    float* __restrict__ out){
  int g = blockIdx.x;
  int t = threadIdx.x;
  __shared__ float sin_[32 * 30];
  __shared__ float c1[16 * 26];
  __shared__ float c2[32 * 22];
  __shared__ float d1[128];
  __shared__ float w1s[16 * 32 * 5];
  __shared__ float w2s[32 * 16 * 5];

  for (int i = t; i < 960; i += 128)  sin_[i] = pooled[(size_t)g * 960 + i];
  for (int i = t; i < 2560; i += 128) w1s[i] = cw1[i];
  for (int i = t; i < 2560; i += 128) w2s[i] = cw2[i];
  __syncthreads();

  for (int q = t; q < 16 * 26; q += 128){
    int o = q / 26, tt = q % 26;
    float acc = cb1[o];
    const float* wo = &w1s[o * 160];
    for (int i = 0; i < 32; i++){
      const float* si = &sin_[i * 30 + tt];
      #pragma unroll
      for (int k = 0; k < 5; k++) acc = fmaf(si[k], wo[i * 5 + k], acc);
    }
    c1[q] = fmaxf(acc, 0.f);
  }
  __syncthreads();

  for (int q = t; q < 32 * 22; q += 128){
    int o = q / 22, tt = q % 22;
    float acc = cb2[o];
    const float* wo = &w2s[o * 80];
    for (int i = 0; i < 16; i++){
      const float* si = &c1[i * 26 + tt];
      #pragma unroll
      for (int k = 0; k < 5; k++) acc = fmaf(si[k], wo[i * 5 + k], acc);
    }
    c2[q] = fmaxf(acc, 0.f);
  }
  __syncthreads();

  {
    float acc = lb1[t];
    for (int j = 0; j < 704; j++) acc = fmaf(c2[j], lw1[(size_t)j * 128 + t], acc);
    d1[t] = fmaxf(acc, 0.f);
  }
  __syncthreads();

  if (t == 0){
    float acc = lb2[0];
    for (int o = 0; o < 128; o++) acc = fmaf(d1[o], lw2[o], acc);
    out[g] = acc;
  }
}

// ---------------- launch ----------------
extern "C" void kernel_launch(void* const* d_in, const int* in_sizes, int n_in,
                              void* d_out, int out_size, void* d_ws, size_t ws_size,
                              hipStream_t stream){
  const float* x     = (const float*)d_in[0];
  const int*   ei    = (const int*)  d_in[1];
  const int*   batch = (const int*)  d_in[2];
  const float* W1  = (const float*)d_in[4];
  const float* b1  = (const float*)d_in[5];
  const float* W2  = (const float*)d_in[6];
  const float* b2  = (const float*)d_in[7];
  const float* W3  = (const float*)d_in[8];
  const float* b3  = (const float*)d_in[9];
  const float* cw1 = (const float*)d_in[10];
  const float* cb1 = (const float*)d_in[11];
  const float* cw2 = (const float*)d_in[12];
  const float* cb2 = (const float*)d_in[13];
  const float* lw1 = (const float*)d_in[14];
  const float* lb1 = (const float*)d_in[15];
  const float* lw2 = (const float*)d_in[16];
  const float* lb2 = (const float*)d_in[17];

  int N = in_sizes[0] / 9;
  int E = in_sizes[1] / 2;
  int G = out_size;
  const int* srcs = ei;
  const int* dsts = ei + E;
  int NB = ceil_div_i(N, BNODES);           // 1954 for N=250000
  int segsz = ceil_div_i(E, NSEG);

  char* base = (char*)d_ws;
  size_t off = 0;
  auto alloc = [&](size_t bytes) -> void* {
    off = (off + 255) & ~(size_t)255;
    void* r = base + off; off += bytes; return r;
  };
  float* dis    = (float*)alloc((size_t)N * 4);
  float* H      = (float*)alloc((size_t)N * 32 * 4);
  float* A      = (float*)alloc((size_t)N * 32 * 4);
  float* pooled = (float*)alloc((size_t)G * 32 * SORTK * 4);
  int*   degcnt = (int*)alloc((size_t)N * 4);
  int*   offs   = (int*)alloc((size_t)(N + 1) * 4);
  int*   csr    = (int*)alloc((size_t)E * 4);
  int*   bsum   = (int*)alloc((size_t)ceil_div_i(N, 256) * 4);
  int*   gst    = (int*)alloc((size_t)(G + 1) * 4);
  int*   hist   = (int*)alloc((size_t)NSEG * NB * 4);
  int*   segoff = (int*)alloc((size_t)NSEG * NB * 4);
  int*   bbase  = (int*)alloc((size_t)(NB + 1) * 4);
  int*   staging = (int*)H;   // alias: H written only after CSR build completes
  (void)ws_size; (void)n_in;

  hipMemsetAsync(pooled, 0, (size_t)G * 32 * SORTK * 4, stream);

  // CSR build: histogram multisplit (no global atomics)
  hist_kernel<<<NSEG, 256, 0, stream>>>(dsts, hist, E, NB, segsz);
  segscan_kernel<<<1, 1024, 0, stream>>>(hist, segoff, bbase, NB, NSEG);
  scatter_kernel<<<NSEG, 256, 0, stream>>>(dsts, segoff, bbase, staging, E, NB, segsz);
  bucket_sort_kernel<<<NB, BNODES, 0, stream>>>(bbase, staging, srcs, csr, degcnt, dis, N, NB, E);

  // global offsets for agg
  int nb = ceil_div_i(N, 256);
  scanA<<<nb, 256, 0, stream>>>(degcnt, bsum, N);
  scanB<<<1, 1024, 0, stream>>>(bsum, nb, offs, N);
  scanC<<<nb, 256, 0, stream>>>(degcnt, bsum, offs, N);

  int nt = ceil_div_i((long long)N * 32, 256);
  node_matmul<9><<<nt, 256, 0, stream>>>(x, W1, H, N);
  agg_kernel<<<nt, 256, 0, stream>>>(H, offs, csr, dis, b1, A, N);
  node_matmul<32><<<nt, 256, 0, stream>>>(A, W2, H, N);
  agg_kernel<<<nt, 256, 0, stream>>>(H, offs, csr, dis, b2, A, N);
  node_matmul<32><<<nt, 256, 0, stream>>>(A, W3, H, N);
  agg_kernel<<<nt, 256, 0, stream>>>(H, offs, csr, dis, b3, A, N);

  gstarts_kernel<<<ceil_div_i(G + 1, 256), 256, 0, stream>>>(batch, gst, N, G);
  sort_pool_kernel<<<G, 128, 0, stream>>>(A, gst, pooled);
  head_kernel<<<G, 128, 0, stream>>>(pooled, cw1, cb1, cw2, cb2, lw1, lb1, lw2, lb2,
                                     (float*)d_out);
}

// Round 4
// 821.863 us; speedup vs baseline: 1.5140x; 1.1361x over previous
//
#include <hip/hip_runtime.h>

typedef unsigned long long ull;

#define HIDDEN 32
#define SORTK 30
#define SP_CAP 3072
#define BSH 7                 // 128 nodes per bucket
#define BNODES (1 << BSH)
#define BCAP 1536             // LDS staging per bucket (mean ~1280, sd ~36; 7-sigma)
#define HMAX 2048             // max buckets supported (N <= 262144)
#define NSEG 64               // scatter segments
#define SRC_BITS 18
#define SRC_MASK ((1u << SRC_BITS) - 1)
#define EID_SH  SRC_BITS      // eid at bits 18..39
#define LD_SH   (SRC_BITS + 22)  // local_dst at bits 40..46

static inline int ceil_div_i(long long a, int b){ return (int)((a + b - 1) / b); }

// ---------------- phase 1: per-segment LDS histogram ----------------
__global__ __launch_bounds__(256) void hist_kernel(const int* __restrict__ dsts,
                                                   int* __restrict__ hist,
                                                   int E, int NB, int segsz){
  __shared__ int h[HMAX];
  for (int i = threadIdx.x; i < NB; i += 256) h[i] = 0;
  __syncthreads();
  int seg = blockIdx.x;
  int e0 = seg * segsz;
  int e1 = e0 + segsz; if (e1 > E) e1 = E;
  for (int e = e0 + threadIdx.x; e < e1; e += 256)
    atomicAdd(&h[dsts[e] >> BSH], 1);
  __syncthreads();
  for (int i = threadIdx.x; i < NB; i += 256) hist[seg * NB + i] = h[i];
}

// ---------------- phase 2: per-bucket seg-prefix + bucket-base scan (1 block) ----------
__global__ __launch_bounds__(1024) void segscan_kernel(const int* __restrict__ hist,
                                                       int* __restrict__ segoff,
                                                       int* __restrict__ bbase,
                                                       int NB, int S){
  int t = threadIdx.x;
  int b0 = t * 2, b1 = t * 2 + 1;
  int tot0 = 0, tot1 = 0;
  if (b0 < NB){ int run = 0; for (int s = 0; s < S; s++){ int v = hist[s * NB + b0]; segoff[s * NB + b0] = run; run += v; } tot0 = run; }
  if (b1 < NB){ int run = 0; for (int s = 0; s < S; s++){ int v = hist[s * NB + b1]; segoff[s * NB + b1] = run; run += v; } tot1 = run; }
  int pair = tot0 + tot1;
  int lane = t & 63, wid = t >> 6;
  int x = pair;
  for (int o = 1; o < 64; o <<= 1){ int y = __shfl_up(x, o, 64); if (lane >= o) x += y; }
  __shared__ int wsum[16]; __shared__ int woff[16];
  if (lane == 63) wsum[wid] = x;
  __syncthreads();
  if (t == 0){ int run = 0; for (int w = 0; w < 16; w++){ woff[w] = run; run += wsum[w]; } }
  __syncthreads();
  int excl = x - pair + woff[wid];
  if (b0 < NB) bbase[b0] = excl;
  if (b1 < NB) bbase[b1] = excl + tot0;
}

// ---------------- phase 3: scatter 64-bit (ld,eid,src) with block-private regions ------
__global__ __launch_bounds__(256) void scatter_kernel(const int* __restrict__ dsts,
                                                      const int* __restrict__ srcs,
                                                      const int* __restrict__ segoff,
                                                      const int* __restrict__ bbase,
                                                      ull* __restrict__ staging,
                                                      int E, int NB, int segsz){
  __shared__ int cur[HMAX];
  int seg = blockIdx.x;
  for (int i = threadIdx.x; i < NB; i += 256) cur[i] = segoff[seg * NB + i] + bbase[i];
  __syncthreads();
  int e0 = seg * segsz;
  int e1 = e0 + segsz; if (e1 > E) e1 = E;
  for (int e = e0 + threadIdx.x; e < e1; e += 256){
    int d = dsts[e];
    int slot = atomicAdd(&cur[d >> BSH], 1);
    staging[slot] = ((ull)(d & (BNODES - 1)) << LD_SH) | ((ull)e << EID_SH)
                  | (ull)(unsigned)srcs[e];
  }
}

// ---------------- phase 4: per-bucket LDS sort + dis + offs + CSR (src inline) --------
__global__ __launch_bounds__(BNODES) void bucket_sort_kernel(
    const int* __restrict__ bbase, const ull* __restrict__ staging,
    int* __restrict__ csr, int* __restrict__ offs,
    float* __restrict__ dis, int N, int NB, int E){
  __shared__ ull ebuf[BCAP];
  __shared__ ull obuf[BCAP];
  __shared__ int cnt[BNODES];
  __shared__ int cur[BNODES];
  __shared__ int w0tot;
  int b = blockIdx.x, t = threadIdx.x;
  int n0 = b << BSH;
  int n1 = n0 + BNODES; if (n1 > N) n1 = N;
  int gbeg = bbase[b];
  int gend = (b + 1 < NB) ? bbase[b + 1] : E;
  int cnt_all = gend - gbeg;
  cnt[t] = 0;
  __syncthreads();

  if (cnt_all <= BCAP){
    // load + per-node count
    for (int i = t; i < cnt_all; i += BNODES){
      ull k = staging[gbeg + i];
      ebuf[i] = k;
      atomicAdd(&cnt[(int)(k >> LD_SH)], 1);
    }
    __syncthreads();
    // exclusive prefix over 128 counts (2 waves)
    int v = cnt[t];
    int lane = t & 63, wid = t >> 6;
    int x = v;
    for (int o = 1; o < 64; o <<= 1){ int y = __shfl_up(x, o, 64); if (lane >= o) x += y; }
    if (wid == 0 && lane == 63) w0tot = x;
    __syncthreads();
    int ls = x - v + (wid ? w0tot : 0);
    cur[t] = ls;
    int n = n0 + t;
    if (n < n1){
      float dd = (float)v + 1.0f;
      dis[n]  = __fdiv_rn(1.0f, __fsqrt_rn(dd));
      offs[n] = gbeg + ls;
    }
    __syncthreads();
    // scatter into per-node runs (LDS atomics)
    for (int i = t; i < cnt_all; i += BNODES){
      ull k = ebuf[i];
      int pos = atomicAdd(&cur[(int)(k >> LD_SH)], 1);
      obuf[pos] = k;
    }
    __syncthreads();
    // insertion-sort own run by 64-bit key == (dst,eid) order (eid globally unique)
    for (int i = ls + 1; i < ls + v; i++){
      ull k = obuf[i]; int j = i - 1;
      while (j >= ls && obuf[j] > k){ obuf[j + 1] = obuf[j]; j--; }
      obuf[j + 1] = k;
    }
    __syncthreads();
    // coalesced CSR write (src in payload — no global gather)
    for (int i = t; i < cnt_all; i += BNODES)
      csr[gbeg + i] = (int)(obuf[i] & SRC_MASK);
  } else {
    // statistically unreachable fallback (correct, slow)
    int n = n0 + t;
    int deg = 0;
    if (n < n1){
      for (int i = gbeg; i < gend; i++) if ((int)(staging[i] >> LD_SH) == t) deg++;
      float dd = (float)deg + 1.0f;
      dis[n] = __fdiv_rn(1.0f, __fsqrt_rn(dd));
    }
    cnt[t] = (n < n1) ? deg : 0;
    __syncthreads();
    if (n < n1){
      int ls = gbeg; for (int q = 0; q < t; q++) ls += cnt[q];
      offs[n] = ls;
      ull prev = 0;
      for (int o = 0; o < deg; o++){
        ull best = ~0ull;
        for (int i = gbeg; i < gend; i++){
          ull k = staging[i];
          if ((int)(k >> LD_SH) == t && (o == 0 || k > prev) && k < best) best = k;
        }
        csr[ls + o] = (int)(best & SRC_MASK); prev = best;
      }
    }
  }
  if (b == 0 && t == 0) offs[N] = E;
}

// ---------------- per-node matmul h = x @ W ----------------
template<int K>
__global__ void node_matmul(const float* __restrict__ xin, const float* __restrict__ W,
                            float* __restrict__ H, int N){
  __shared__ float Ws[K * 32];
  for (int i = threadIdx.x; i < K * 32; i += blockDim.x) Ws[i] = W[i];
  __syncthreads();
  int tid = blockIdx.x * blockDim.x + threadIdx.x;
  int n = tid >> 5, c = tid & 31;
  if (n >= N) return;
  const float* xr = xin + (size_t)n * K;
  float acc = 0.f;
  #pragma unroll
  for (int k = 0; k < K; k++) acc = fmaf(xr[k], Ws[k * 32 + c], acc);
  H[(size_t)n * 32 + c] = acc;
}

// ---------------- GCN aggregation (deterministic edge order, 4x pipelined) ----------
__global__ void agg_kernel(const float* __restrict__ H, const int* __restrict__ offsets,
                           const int* __restrict__ csr, const float* __restrict__ dis,
                           const float* __restrict__ bias, float* __restrict__ A, int N){
  int tid = blockIdx.x * blockDim.x + threadIdx.x;
  int n = tid >> 5, c = tid & 31;
  if (n >= N) return;
  float dn = dis[n];
  int s = offsets[n], e = offsets[n + 1];
  float acc = 0.f;
  int i = s;
  for (; i + 4 <= e; i += 4){
    int s0 = csr[i], s1 = csr[i+1], s2 = csr[i+2], s3 = csr[i+3];
    float h0 = H[(size_t)s0*32+c], h1 = H[(size_t)s1*32+c];
    float h2 = H[(size_t)s2*32+c], h3 = H[(size_t)s3*32+c];
    float w0 = __fmul_rn(dis[s0], dn), w1 = __fmul_rn(dis[s1], dn);
    float w2 = __fmul_rn(dis[s2], dn), w3 = __fmul_rn(dis[s3], dn);
    acc = __fadd_rn(acc, __fmul_rn(h0, w0));   // exact reference order preserved
    acc = __fadd_rn(acc, __fmul_rn(h1, w1));
    acc = __fadd_rn(acc, __fmul_rn(h2, w2));
    acc = __fadd_rn(acc, __fmul_rn(h3, w3));
  }
  for (; i < e; i++){
    int sr = csr[i];
    float w = __fmul_rn(dis[sr], dn);
    acc = __fadd_rn(acc, __fmul_rn(H[(size_t)sr * 32 + c], w));
  }
  float selfw = __fmul_rn(dn, dn);
  float v = __fadd_rn(acc, __fmul_rn(H[(size_t)n * 32 + c], selfw));
  v = __fadd_rn(v, bias[c]);
  A[(size_t)n * 32 + c] = fmaxf(v, 0.f);
}

// ---------------- graph boundaries (batch is sorted) ----------------
__global__ void gstarts_kernel(const int* __restrict__ batch, int* __restrict__ gstarts,
                               int N, int G){
  int g = blockIdx.x * blockDim.x + threadIdx.x;
  if (g > G) return;
  int lo = 0, hi = N;
  while (lo < hi){ int mid = (lo + hi) >> 1; if (batch[mid] < g) lo = mid + 1; else hi = mid; }
  gstarts[g] = lo;
}

// ---------------- sort-pool: stable top-30 by key desc, tie by index asc ----------------
__global__ void sort_pool_kernel(const float* __restrict__ A, const int* __restrict__ gstarts,
                                 float* __restrict__ pooled){
  int g = blockIdx.x;
  int s = gstarts[g], e = gstarts[g + 1];
  int c = e - s;
  __shared__ float keys[SP_CAP];
  bool uselds = (c <= SP_CAP);
  if (uselds){
    for (int i = threadIdx.x; i < c; i += blockDim.x) keys[i] = A[(size_t)(s + i) * 32 + 31];
  }
  __syncthreads();
  for (int i = threadIdx.x; i < c; i += blockDim.x){
    float ki = uselds ? keys[i] : A[(size_t)(s + i) * 32 + 31];
    int rank = 0; bool sel = true;
    for (int j = 0; j < c; j++){
      float kj = uselds ? keys[j] : A[(size_t)(s + j) * 32 + 31];
      if (kj > ki || (kj == ki && j < i)){
        if (++rank >= SORTK){ sel = false; break; }
      }
    }
    if (sel){
      for (int ch = 0; ch < 32; ch++)
        pooled[(size_t)g * 32 * SORTK + ch * SORTK + rank] = A[(size_t)(s + i) * 32 + ch];
    }
  }
}

// ---------------- head: conv1 -> conv2 -> dense1 -> dense2, one block per graph ----------
__global__ __launch_bounds__(128) void head_kernel(
    const float* __restrict__ pooled,
    const float* __restrict__ cw1, const float* __restrict__ cb1,
    const float* __restrict__ cw2, const float* __restrict__ cb2,
    const float* __restrict__ lw1, const float* __restrict__ lb1,
    const float* __restrict__ lw2, const float* __restrict__ lb2,
    float* __restrict__ out){
  int g = blockIdx.x;
  int t = threadIdx.x;
  __shared__ float sin_[32 * 30];
  __shared__ float c1[16 * 26];
  __shared__ float c2[32 * 22];
  __shared__ float d1[128];
  __shared__ float w1s[16 * 32 * 5];
  __shared__ float w2s[32 * 16 * 5];

  for (int i = t; i < 960; i += 128)  sin_[i] = pooled[(size_t)g * 960 + i];
  for (int i = t; i < 2560; i += 128) w1s[i] = cw1[i];
  for (int i = t; i < 2560; i += 128) w2s[i] = cw2[i];
  __syncthreads();

  for (int q = t; q < 16 * 26; q += 128){
    int o = q / 26, tt = q % 26;
    float acc = cb1[o];
    const float* wo = &w1s[o * 160];
    for (int i = 0; i < 32; i++){
      const float* si = &sin_[i * 30 + tt];
      #pragma unroll
      for (int k = 0; k < 5; k++) acc = fmaf(si[k], wo[i * 5 + k], acc);
    }
    c1[q] = fmaxf(acc, 0.f);
  }
  __syncthreads();

  for (int q = t; q < 32 * 22; q += 128){
    int o = q / 22, tt = q % 22;
    float acc = cb2[o];
    const float* wo = &w2s[o * 80];
    for (int i = 0; i < 16; i++){
      const float* si = &c1[i * 26 + tt];
      #pragma unroll
      for (int k = 0; k < 5; k++) acc = fmaf(si[k], wo[i * 5 + k], acc);
    }
    c2[q] = fmaxf(acc, 0.f);
  }
  __syncthreads();

  {
    float acc = lb1[t];
    for (int j = 0; j < 704; j++) acc = fmaf(c2[j], lw1[(size_t)j * 128 + t], acc);
    d1[t] = fmaxf(acc, 0.f);
  }
  __syncthreads();

  if (t == 0){
    float acc = lb2[0];
    for (int o = 0; o < 128; o++) acc = fmaf(d1[o], lw2[o], acc);
    out[g] = acc;
  }
}

// ---------------- launch ----------------
extern "C" void kernel_launch(void* const* d_in, const int* in_sizes, int n_in,
                              void* d_out, int out_size, void* d_ws, size_t ws_size,
                              hipStream_t stream){
  const float* x     = (const float*)d_in[0];
  const int*   ei    = (const int*)  d_in[1];
  const int*   batch = (const int*)  d_in[2];
  const float* W1  = (const float*)d_in[4];
  const float* b1  = (const float*)d_in[5];
  const float* W2  = (const float*)d_in[6];
  const float* b2  = (const float*)d_in[7];
  const float* W3  = (const float*)d_in[8];
  const float* b3  = (const float*)d_in[9];
  const float* cw1 = (const float*)d_in[10];
  const float* cb1 = (const float*)d_in[11];
  const float* cw2 = (const float*)d_in[12];
  const float* cb2 = (const float*)d_in[13];
  const float* lw1 = (const float*)d_in[14];
  const float* lb1 = (const float*)d_in[15];
  const float* lw2 = (const float*)d_in[16];
  const float* lb2 = (const float*)d_in[17];

  int N = in_sizes[0] / 9;
  int E = in_sizes[1] / 2;
  int G = out_size;
  const int* srcs = ei;
  const int* dsts = ei + E;
  int NB = ceil_div_i(N, BNODES);           // 1954 for N=250000
  int segsz = ceil_div_i(E, NSEG);

  char* base = (char*)d_ws;
  size_t off = 0;
  auto alloc = [&](size_t bytes) -> void* {
    off = (off + 255) & ~(size_t)255;
    void* r = base + off; off += bytes; return r;
  };
  float* dis    = (float*)alloc((size_t)N * 4);
  float* H      = (float*)alloc((size_t)N * 32 * 4);   // also aliased as staging (E*8 <= N*128)
  float* A      = (float*)alloc((size_t)N * 32 * 4);
  float* pooled = (float*)alloc((size_t)G * 32 * SORTK * 4);
  int*   offs   = (int*)alloc((size_t)(N + 1) * 4);
  int*   csr    = (int*)alloc((size_t)E * 4);
  int*   gst    = (int*)alloc((size_t)(G + 1) * 4);
  int*   hist   = (int*)alloc((size_t)NSEG * NB * 4);
  int*   segoff = (int*)alloc((size_t)NSEG * NB * 4);
  int*   bbase  = (int*)alloc((size_t)(NB + 1) * 4);
  ull*   staging = (ull*)H;   // alias: H written only after CSR build completes
  (void)ws_size; (void)n_in;

  hipMemsetAsync(pooled, 0, (size_t)G * 32 * SORTK * 4, stream);

  // CSR build: histogram multisplit (no global atomics), src carried in payload
  hist_kernel<<<NSEG, 256, 0, stream>>>(dsts, hist, E, NB, segsz);
  segscan_kernel<<<1, 1024, 0, stream>>>(hist, segoff, bbase, NB, NSEG);
  scatter_kernel<<<NSEG, 256, 0, stream>>>(dsts, srcs, segoff, bbase, staging, E, NB, segsz);
  bucket_sort_kernel<<<NB, BNODES, 0, stream>>>(bbase, staging, csr, offs, dis, N, NB, E);

  int nt = ceil_div_i((long long)N * 32, 256);
  node_matmul<9><<<nt, 256, 0, stream>>>(x, W1, H, N);
  agg_kernel<<<nt, 256, 0, stream>>>(H, offs, csr, dis, b1, A, N);
  node_matmul<32><<<nt, 256, 0, stream>>>(A, W2, H, N);
  agg_kernel<<<nt, 256, 0, stream>>>(H, offs, csr, dis, b2, A, N);
  node_matmul<32><<<nt, 256, 0, stream>>>(A, W3, H, N);
  agg_kernel<<<nt, 256, 0, stream>>>(H, offs, csr, dis, b3, A, N);

  gstarts_kernel<<<ceil_div_i(G + 1, 256), 256, 0, stream>>>(batch, gst, N, G);
  sort_pool_kernel<<<G, 128, 0, stream>>>(A, gst, pooled);
  head_kernel<<<G, 128, 0, stream>>>(pooled, cw1, cb1, cw2, cb2, lw1, lb1, lw2, lb2,
                                     (float*)d_out);
}

// Round 5
// 696.197 us; speedup vs baseline: 1.7873x; 1.1805x over previous
//
#include <hip/hip_runtime.h>

typedef unsigned long long ull;

#define HIDDEN 32
#define SORTK 30
#define SP_CAP 3072
#define BSH 7                 // 128 nodes per bucket
#define BNODES (1 << BSH)
#define BCAP 1536             // LDS staging per bucket (mean ~1280, sd ~36; 7-sigma)
#define HMAX 2048             // max buckets supported (N <= 262144)
#define NSEG 256              // scatter segments (1 per CU)
#define SRC_BITS 18
#define SRC_MASK ((1u << SRC_BITS) - 1)
#define EID_SH  SRC_BITS      // eid at bits 18..39
#define LD_SH   (SRC_BITS + 22)  // local_dst at bits 40..46

static inline int ceil_div_i(long long a, int b){ return (int)((a + b - 1) / b); }

// ---------------- phase 1: per-segment LDS histogram ----------------
__global__ __launch_bounds__(256) void hist_kernel(const int* __restrict__ dsts,
                                                   int* __restrict__ hist,
                                                   int E, int NB, int segsz){
  __shared__ int h[HMAX];
  for (int i = threadIdx.x; i < NB; i += 256) h[i] = 0;
  __syncthreads();
  int seg = blockIdx.x;
  int e0 = seg * segsz;
  int e1 = e0 + segsz; if (e1 > E) e1 = E;
  for (int e = e0 + threadIdx.x; e < e1; e += 256)
    atomicAdd(&h[dsts[e] >> BSH], 1);
  __syncthreads();
  for (int i = threadIdx.x; i < NB; i += 256) hist[seg * NB + i] = h[i];
}

// ---------------- phase 2a: per-bucket running prefix over segments (grid-parallel) ----
__global__ __launch_bounds__(256) void segscanA(const int* __restrict__ hist,
                                                int* __restrict__ segoff,
                                                int* __restrict__ btot,
                                                int NB, int S){
  int b = blockIdx.x * 256 + threadIdx.x;
  if (b >= NB) return;
  int run = 0;
  for (int s = 0; s < S; s++){        // coalesced: consecutive b => consecutive addrs
    int v = hist[s * NB + b];
    segoff[s * NB + b] = run;
    run += v;
  }
  btot[b] = run;
}

// ---------------- phase 2b: exclusive scan of bucket totals (1 block) ----------------
__global__ __launch_bounds__(1024) void segscanB(const int* __restrict__ btot,
                                                 int* __restrict__ bbase, int NB){
  int t = threadIdx.x;
  int b0 = t * 2, b1 = t * 2 + 1;
  int v0 = (b0 < NB) ? btot[b0] : 0;
  int v1 = (b1 < NB) ? btot[b1] : 0;
  int pair = v0 + v1;
  int lane = t & 63, wid = t >> 6;
  int x = pair;
  for (int o = 1; o < 64; o <<= 1){ int y = __shfl_up(x, o, 64); if (lane >= o) x += y; }
  __shared__ int wsum[16]; __shared__ int woff[16];
  if (lane == 63) wsum[wid] = x;
  __syncthreads();
  if (t == 0){ int run = 0; for (int w = 0; w < 16; w++){ woff[w] = run; run += wsum[w]; } }
  __syncthreads();
  int excl = x - pair + woff[wid];
  if (b0 < NB) bbase[b0] = excl;
  if (b1 < NB) bbase[b1] = excl + v0;
}

// ---------------- phase 3: scatter 64-bit (ld,eid,src) with block-private regions ------
__global__ __launch_bounds__(256) void scatter_kernel(const int* __restrict__ dsts,
                                                      const int* __restrict__ srcs,
                                                      const int* __restrict__ segoff,
                                                      const int* __restrict__ bbase,
                                                      ull* __restrict__ staging,
                                                      int E, int NB, int segsz){
  __shared__ int cur[HMAX];
  int seg = blockIdx.x;
  for (int i = threadIdx.x; i < NB; i += 256) cur[i] = segoff[seg * NB + i] + bbase[i];
  __syncthreads();
  int e0 = seg * segsz;
  int e1 = e0 + segsz; if (e1 > E) e1 = E;
  for (int e = e0 + threadIdx.x; e < e1; e += 256){
    int d = dsts[e];
    int slot = atomicAdd(&cur[d >> BSH], 1);
    staging[slot] = ((ull)(d & (BNODES - 1)) << LD_SH) | ((ull)e << EID_SH)
                  | (ull)(unsigned)srcs[e];
  }
}

// ---------------- phase 4: per-bucket LDS sort + dis + offs + CSR (src inline) --------
__global__ __launch_bounds__(BNODES) void bucket_sort_kernel(
    const int* __restrict__ bbase, const ull* __restrict__ staging,
    int* __restrict__ csr, int* __restrict__ offs,
    float* __restrict__ dis, int N, int NB, int E){
  __shared__ ull ebuf[BCAP];
  __shared__ ull obuf[BCAP];
  __shared__ int cnt[BNODES];
  __shared__ int cur[BNODES];
  __shared__ int w0tot;
  int b = blockIdx.x, t = threadIdx.x;
  int n0 = b << BSH;
  int n1 = n0 + BNODES; if (n1 > N) n1 = N;
  int gbeg = bbase[b];
  int gend = (b + 1 < NB) ? bbase[b + 1] : E;
  int cnt_all = gend - gbeg;
  cnt[t] = 0;
  __syncthreads();

  if (cnt_all <= BCAP){
    for (int i = t; i < cnt_all; i += BNODES){
      ull k = staging[gbeg + i];
      ebuf[i] = k;
      atomicAdd(&cnt[(int)(k >> LD_SH)], 1);
    }
    __syncthreads();
    int v = cnt[t];
    int lane = t & 63, wid = t >> 6;
    int x = v;
    for (int o = 1; o < 64; o <<= 1){ int y = __shfl_up(x, o, 64); if (lane >= o) x += y; }
    if (wid == 0 && lane == 63) w0tot = x;
    __syncthreads();
    int ls = x - v + (wid ? w0tot : 0);
    cur[t] = ls;
    int n = n0 + t;
    if (n < n1){
      float dd = (float)v + 1.0f;
      dis[n]  = __fdiv_rn(1.0f, __fsqrt_rn(dd));
      offs[n] = gbeg + ls;
    }
    __syncthreads();
    for (int i = t; i < cnt_all; i += BNODES){
      ull k = ebuf[i];
      int pos = atomicAdd(&cur[(int)(k >> LD_SH)], 1);
      obuf[pos] = k;
    }
    __syncthreads();
    // insertion-sort own run by 64-bit key == (dst,eid) order (eid globally unique)
    for (int i = ls + 1; i < ls + v; i++){
      ull k = obuf[i]; int j = i - 1;
      while (j >= ls && obuf[j] > k){ obuf[j + 1] = obuf[j]; j--; }
      obuf[j + 1] = k;
    }
    __syncthreads();
    for (int i = t; i < cnt_all; i += BNODES)
      csr[gbeg + i] = (int)(obuf[i] & SRC_MASK);
  } else {
    // statistically unreachable fallback (correct, slow)
    int n = n0 + t;
    int deg = 0;
    if (n < n1){
      for (int i = gbeg; i < gend; i++) if ((int)(staging[i] >> LD_SH) == t) deg++;
      float dd = (float)deg + 1.0f;
      dis[n] = __fdiv_rn(1.0f, __fsqrt_rn(dd));
    }
    cnt[t] = (n < n1) ? deg : 0;
    __syncthreads();
    if (n < n1){
      int ls = gbeg; for (int q = 0; q < t; q++) ls += cnt[q];
      offs[n] = ls;
      ull prev = 0;
      for (int o = 0; o < deg; o++){
        ull best = ~0ull;
        for (int i = gbeg; i < gend; i++){
          ull k = staging[i];
          if ((int)(k >> LD_SH) == t && (o == 0 || k > prev) && k < best) best = k;
        }
        csr[ls + o] = (int)(best & SRC_MASK); prev = best;
      }
    }
  }
  if (b == 0 && t == 0) offs[N] = E;
}

// ---------------- per-node matmul h = x @ W ----------------
template<int K>
__global__ void node_matmul(const float* __restrict__ xin, const float* __restrict__ W,
                            float* __restrict__ H, int N){
  __shared__ float Ws[K * 32];
  for (int i = threadIdx.x; i < K * 32; i += blockDim.x) Ws[i] = W[i];
  __syncthreads();
  int tid = blockIdx.x * blockDim.x + threadIdx.x;
  int n = tid >> 5, c = tid & 31;
  if (n >= N) return;
  const float* xr = xin + (size_t)n * K;
  float acc = 0.f;
  #pragma unroll
  for (int k = 0; k < K; k++) acc = fmaf(xr[k], Ws[k * 32 + c], acc);
  H[(size_t)n * 32 + c] = acc;
}

// ---------------- GCN aggregation: 8 lanes/node x float4, exact edge order ----------
__device__ __forceinline__ float4 acc_edge(float4 a, float4 h, float w){
  a.x = __fadd_rn(a.x, __fmul_rn(h.x, w));
  a.y = __fadd_rn(a.y, __fmul_rn(h.y, w));
  a.z = __fadd_rn(a.z, __fmul_rn(h.z, w));
  a.w = __fadd_rn(a.w, __fmul_rn(h.w, w));
  return a;
}

__global__ __launch_bounds__(256) void agg_kernel(const float* __restrict__ H,
                           const int* __restrict__ offsets,
                           const int* __restrict__ csr, const float* __restrict__ dis,
                           const float* __restrict__ bias, float* __restrict__ A, int N){
  int tid = blockIdx.x * 256 + threadIdx.x;
  int n = tid >> 3, qw = tid & 7;         // 8 lanes per node, 4 channels per lane
  if (n >= N) return;
  const float4* __restrict__ H4 = (const float4*)H;
  float dn = dis[n];
  int s = offsets[n], e = offsets[n + 1];
  float4 acc = make_float4(0.f, 0.f, 0.f, 0.f);
  int i = s;
  for (; i + 4 <= e; i += 4){
    int s0 = csr[i], s1 = csr[i+1], s2 = csr[i+2], s3 = csr[i+3];
    float4 h0 = H4[(size_t)s0 * 8 + qw];
    float4 h1 = H4[(size_t)s1 * 8 + qw];
    float4 h2 = H4[(size_t)s2 * 8 + qw];
    float4 h3 = H4[(size_t)s3 * 8 + qw];
    float w0 = __fmul_rn(dis[s0], dn), w1 = __fmul_rn(dis[s1], dn);
    float w2 = __fmul_rn(dis[s2], dn), w3 = __fmul_rn(dis[s3], dn);
    acc = acc_edge(acc, h0, w0);          // per-channel order == reference order
    acc = acc_edge(acc, h1, w1);
    acc = acc_edge(acc, h2, w2);
    acc = acc_edge(acc, h3, w3);
  }
  for (; i < e; i++){
    int sr = csr[i];
    float w = __fmul_rn(dis[sr], dn);
    acc = acc_edge(acc, H4[(size_t)sr * 8 + qw], w);
  }
  float4 hn = H4[(size_t)n * 8 + qw];
  float sw = __fmul_rn(dn, dn);
  float4 bb = ((const float4*)bias)[qw];
  float4 v;
  v.x = fmaxf(__fadd_rn(__fadd_rn(acc.x, __fmul_rn(hn.x, sw)), bb.x), 0.f);
  v.y = fmaxf(__fadd_rn(__fadd_rn(acc.y, __fmul_rn(hn.y, sw)), bb.y), 0.f);
  v.z = fmaxf(__fadd_rn(__fadd_rn(acc.z, __fmul_rn(hn.z, sw)), bb.z), 0.f);
  v.w = fmaxf(__fadd_rn(__fadd_rn(acc.w, __fmul_rn(hn.w, sw)), bb.w), 0.f);
  ((float4*)A)[(size_t)n * 8 + qw] = v;
}

// ---------------- graph boundaries (batch is sorted) ----------------
__global__ void gstarts_kernel(const int* __restrict__ batch, int* __restrict__ gstarts,
                               int N, int G){
  int g = blockIdx.x * blockDim.x + threadIdx.x;
  if (g > G) return;
  int lo = 0, hi = N;
  while (lo < hi){ int mid = (lo + hi) >> 1; if (batch[mid] < g) lo = mid + 1; else hi = mid; }
  gstarts[g] = lo;
}

// ---------------- sort-pool: stable top-30 by key desc, tie by index asc ----------------
__global__ void sort_pool_kernel(const float* __restrict__ A, const int* __restrict__ gstarts,
                                 float* __restrict__ pooled){
  int g = blockIdx.x;
  int s = gstarts[g], e = gstarts[g + 1];
  int c = e - s;
  __shared__ float keys[SP_CAP];
  bool uselds = (c <= SP_CAP);
  if (uselds){
    for (int i = threadIdx.x; i < c; i += blockDim.x) keys[i] = A[(size_t)(s + i) * 32 + 31];
  }
  __syncthreads();
  for (int i = threadIdx.x; i < c; i += blockDim.x){
    float ki = uselds ? keys[i] : A[(size_t)(s + i) * 32 + 31];
    int rank = 0; bool sel = true;
    for (int j = 0; j < c; j++){
      float kj = uselds ? keys[j] : A[(size_t)(s + j) * 32 + 31];
      if (kj > ki || (kj == ki && j < i)){
        if (++rank >= SORTK){ sel = false; break; }
      }
    }
    if (sel){
      for (int ch = 0; ch < 32; ch++)
        pooled[(size_t)g * 32 * SORTK + ch * SORTK + rank] = A[(size_t)(s + i) * 32 + ch];
    }
  }
}

// ---------------- head: conv1 -> conv2 -> dense1 -> dense2, one block per graph ----------
__global__ __launch_bounds__(128) void head_kernel(
    const float* __restrict__ pooled,
    const float* __restrict__ cw1, const float* __restrict__ cb1,
    const float* __restrict__ cw2, const float* __restrict__ cb2,
    const float* __restrict__ lw1, const float* __restrict__ lb1,
    const float* __restrict__ lw2, const float* __restrict__ lb2,
    float* __restrict__ out){
  int g = blockIdx.x;
  int t = threadIdx.x;
  __shared__ float sin_[32 * 30];
  __shared__ float c1[16 * 26];
  __shared__ float c2[32 * 22];
  __shared__ float d1[128];
  __shared__ float w1s[16 * 32 * 5];
  __shared__ float w2s[32 * 16 * 5];

  for (int i = t; i < 960; i += 128)  sin_[i] = pooled[(size_t)g * 960 + i];
  for (int i = t; i < 2560; i += 128) w1s[i] = cw1[i];
  for (int i = t; i < 2560; i += 128) w2s[i] = cw2[i];
  __syncthreads();

  for (int q = t; q < 16 * 26; q += 128){
    int o = q / 26, tt = q % 26;
    float acc = cb1[o];
    const float* wo = &w1s[o * 160];
    for (int i = 0; i < 32; i++){
      const float* si = &sin_[i * 30 + tt];
      #pragma unroll
      for (int k = 0; k < 5; k++) acc = fmaf(si[k], wo[i * 5 + k], acc);
    }
    c1[q] = fmaxf(acc, 0.f);
  }
  __syncthreads();

  for (int q = t; q < 32 * 22; q += 128){
    int o = q / 22, tt = q % 22;
    float acc = cb2[o];
    const float* wo = &w2s[o * 80];
    for (int i = 0; i < 16; i++){
      const float* si = &c1[i * 26 + tt];
      #pragma unroll
      for (int k = 0; k < 5; k++) acc = fmaf(si[k], wo[i * 5 + k], acc);
    }
    c2[q] = fmaxf(acc, 0.f);
  }
  __syncthreads();

  {
    float acc = lb1[t];
    for (int j = 0; j < 704; j++) acc = fmaf(c2[j], lw1[(size_t)j * 128 + t], acc);
    d1[t] = fmaxf(acc, 0.f);
  }
  __syncthreads();

  if (t == 0){
    float acc = lb2[0];
    for (int o = 0; o < 128; o++) acc = fmaf(d1[o], lw2[o], acc);
    out[g] = acc;
  }
}

// ---------------- launch ----------------
extern "C" void kernel_launch(void* const* d_in, const int* in_sizes, int n_in,
                              void* d_out, int out_size, void* d_ws, size_t ws_size,
                              hipStream_t stream){
  const float* x     = (const float*)d_in[0];
  const int*   ei    = (const int*)  d_in[1];
  const int*   batch = (const int*)  d_in[2];
  const float* W1  = (const float*)d_in[4];
  const float* b1  = (const float*)d_in[5];
  const float* W2  = (const float*)d_in[6];
  const float* b2  = (const float*)d_in[7];
  const float* W3  = (const float*)d_in[8];
  const float* b3  = (const float*)d_in[9];
  const float* cw1 = (const float*)d_in[10];
  const float* cb1 = (const float*)d_in[11];
  const float* cw2 = (const float*)d_in[12];
  const float* cb2 = (const float*)d_in[13];
  const float* lw1 = (const float*)d_in[14];
  const float* lb1 = (const float*)d_in[15];
  const float* lw2 = (const float*)d_in[16];
  const float* lb2 = (const float*)d_in[17];

  int N = in_sizes[0] / 9;
  int E = in_sizes[1] / 2;
  int G = out_size;
  const int* srcs = ei;
  const int* dsts = ei + E;
  int NB = ceil_div_i(N, BNODES);           // 1954 for N=250000
  int segsz = ceil_div_i(E, NSEG);

  char* base = (char*)d_ws;
  size_t off = 0;
  auto alloc = [&](size_t bytes) -> void* {
    off = (off + 255) & ~(size_t)255;
    void* r = base + off; off += bytes; return r;
  };
  float* dis    = (float*)alloc((size_t)N * 4);
  float* H      = (float*)alloc((size_t)N * 32 * 4);   // also aliased as staging (E*8 <= N*128)
  float* A      = (float*)alloc((size_t)N * 32 * 4);
  float* pooled = (float*)alloc((size_t)G * 32 * SORTK * 4);
  int*   offs   = (int*)alloc((size_t)(N + 1) * 4);
  int*   csr    = (int*)alloc((size_t)E * 4);
  int*   gst    = (int*)alloc((size_t)(G + 1) * 4);
  int*   hist   = (int*)alloc((size_t)NSEG * NB * 4);
  int*   segoff = (int*)alloc((size_t)NSEG * NB * 4);
  int*   btot   = (int*)alloc((size_t)NB * 4);
  int*   bbase  = (int*)alloc((size_t)(NB + 1) * 4);
  ull*   staging = (ull*)H;   // alias: H written only after CSR build completes
  (void)ws_size; (void)n_in;

  hipMemsetAsync(pooled, 0, (size_t)G * 32 * SORTK * 4, stream);

  // CSR build: histogram multisplit (no global atomics), src carried in payload
  hist_kernel<<<NSEG, 256, 0, stream>>>(dsts, hist, E, NB, segsz);
  segscanA<<<ceil_div_i(NB, 256), 256, 0, stream>>>(hist, segoff, btot, NB, NSEG);
  segscanB<<<1, 1024, 0, stream>>>(btot, bbase, NB);
  scatter_kernel<<<NSEG, 256, 0, stream>>>(dsts, srcs, segoff, bbase, staging, E, NB, segsz);
  bucket_sort_kernel<<<NB, BNODES, 0, stream>>>(bbase, staging, csr, offs, dis, N, NB, E);

  int ntm = ceil_div_i((long long)N * 32, 256);
  int nta = ceil_div_i((long long)N * 8, 256);
  node_matmul<9><<<ntm, 256, 0, stream>>>(x, W1, H, N);
  agg_kernel<<<nta, 256, 0, stream>>>(H, offs, csr, dis, b1, A, N);
  node_matmul<32><<<ntm, 256, 0, stream>>>(A, W2, H, N);
  agg_kernel<<<nta, 256, 0, stream>>>(H, offs, csr, dis, b2, A, N);
  node_matmul<32><<<ntm, 256, 0, stream>>>(A, W3, H, N);
  agg_kernel<<<nta, 256, 0, stream>>>(H, offs, csr, dis, b3, A, N);

  gstarts_kernel<<<ceil_div_i(G + 1, 256), 256, 0, stream>>>(batch, gst, N, G);
  sort_pool_kernel<<<G, 128, 0, stream>>>(A, gst, pooled);
  head_kernel<<<G, 128, 0, stream>>>(pooled, cw1, cb1, cw2, cb2, lw1, lb1, lw2, lb2,
                                     (float*)d_out);
}

// Round 6
// 666.357 us; speedup vs baseline: 1.8673x; 1.0448x over previous
//
#include <hip/hip_runtime.h>

typedef unsigned long long ull;

#define HIDDEN 32
#define SORTK 30
#define KCAP 1024             // max nodes/graph fast path (mean 122, sd 11)
#define BSH 7                 // 128 nodes per bucket
#define BNODES (1 << BSH)
#define BCAP 1536             // LDS staging per bucket (mean ~1280, sd ~36; 7-sigma)
#define HMAX 2048             // max buckets supported (N <= 262144)
#define NSEG 256              // scatter segments
#define SRC_BITS 18
#define SRC_MASK ((1u << SRC_BITS) - 1)
#define EID_SH  SRC_BITS
#define LD_SH   (SRC_BITS + 22)

static inline int ceil_div_i(long long a, int b){ return (int)((a + b - 1) / b); }

// ---------------- phase 1: per-segment LDS histogram ----------------
__global__ __launch_bounds__(1024) void hist_kernel(const int* __restrict__ dsts,
                                                    int* __restrict__ hist,
                                                    int E, int NB, int segsz){
  __shared__ int h[HMAX];
  for (int i = threadIdx.x; i < NB; i += 1024) h[i] = 0;
  __syncthreads();
  int seg = blockIdx.x;
  int e0 = seg * segsz;
  int e1 = e0 + segsz; if (e1 > E) e1 = E;
  for (int e = e0 + threadIdx.x; e < e1; e += 1024)
    atomicAdd(&h[dsts[e] >> BSH], 1);
  __syncthreads();
  for (int i = threadIdx.x; i < NB; i += 1024) hist[seg * NB + i] = h[i];
}

// ---------------- phase 2a: per-bucket running prefix over segments (grid-parallel) ----
__global__ __launch_bounds__(256) void segscanA(const int* __restrict__ hist,
                                                int* __restrict__ segoff,
                                                int* __restrict__ btot,
                                                int NB, int S){
  int b = blockIdx.x * 256 + threadIdx.x;
  if (b >= NB) return;
  int run = 0;
  for (int s = 0; s < S; s++){
    int v = hist[s * NB + b];
    segoff[s * NB + b] = run;
    run += v;
  }
  btot[b] = run;
}

// ---------------- phase 2b: exclusive scan of bucket totals (1 block) ----------------
__global__ __launch_bounds__(1024) void segscanB(const int* __restrict__ btot,
                                                 int* __restrict__ bbase, int NB){
  int t = threadIdx.x;
  int b0 = t * 2, b1 = t * 2 + 1;
  int v0 = (b0 < NB) ? btot[b0] : 0;
  int v1 = (b1 < NB) ? btot[b1] : 0;
  int pair = v0 + v1;
  int lane = t & 63, wid = t >> 6;
  int x = pair;
  for (int o = 1; o < 64; o <<= 1){ int y = __shfl_up(x, o, 64); if (lane >= o) x += y; }
  __shared__ int wsum[16]; __shared__ int woff[16];
  if (lane == 63) wsum[wid] = x;
  __syncthreads();
  if (t == 0){ int run = 0; for (int w = 0; w < 16; w++){ woff[w] = run; run += wsum[w]; } }
  __syncthreads();
  int excl = x - pair + woff[wid];
  if (b0 < NB) bbase[b0] = excl;
  if (b1 < NB) bbase[b1] = excl + v0;
}

// ---------------- phase 3: scatter 64-bit (ld,eid,src) with block-private regions ------
__global__ __launch_bounds__(1024) void scatter_kernel(const int* __restrict__ dsts,
                                                       const int* __restrict__ srcs,
                                                       const int* __restrict__ segoff,
                                                       const int* __restrict__ bbase,
                                                       ull* __restrict__ staging,
                                                       int E, int NB, int segsz){
  __shared__ int cur[HMAX];
  int seg = blockIdx.x;
  for (int i = threadIdx.x; i < NB; i += 1024) cur[i] = segoff[seg * NB + i] + bbase[i];
  __syncthreads();
  int e0 = seg * segsz;
  int e1 = e0 + segsz; if (e1 > E) e1 = E;
  for (int e = e0 + threadIdx.x; e < e1; e += 1024){
    int d = dsts[e];
    int slot = atomicAdd(&cur[d >> BSH], 1);
    staging[slot] = ((ull)(d & (BNODES - 1)) << LD_SH) | ((ull)e << EID_SH)
                  | (ull)(unsigned)srcs[e];
  }
}

// ---------------- phase 4: per-bucket LDS sort + dis + offs + CSR (src inline) --------
__global__ __launch_bounds__(BNODES) void bucket_sort_kernel(
    const int* __restrict__ bbase, const ull* __restrict__ staging,
    int* __restrict__ csr, int* __restrict__ offs,
    float* __restrict__ dis, int N, int NB, int E){
  __shared__ ull ebuf[BCAP];
  __shared__ ull obuf[BCAP];
  __shared__ int cnt[BNODES];
  __shared__ int cur[BNODES];
  __shared__ int w0tot;
  int b = blockIdx.x, t = threadIdx.x;
  int n0 = b << BSH;
  int n1 = n0 + BNODES; if (n1 > N) n1 = N;
  int gbeg = bbase[b];
  int gend = (b + 1 < NB) ? bbase[b + 1] : E;
  int cnt_all = gend - gbeg;
  cnt[t] = 0;
  __syncthreads();

  if (cnt_all <= BCAP){
    for (int i = t; i < cnt_all; i += BNODES){
      ull k = staging[gbeg + i];
      ebuf[i] = k;
      atomicAdd(&cnt[(int)(k >> LD_SH)], 1);
    }
    __syncthreads();
    int v = cnt[t];
    int lane = t & 63, wid = t >> 6;
    int x = v;
    for (int o = 1; o < 64; o <<= 1){ int y = __shfl_up(x, o, 64); if (lane >= o) x += y; }
    if (wid == 0 && lane == 63) w0tot = x;
    __syncthreads();
    int ls = x - v + (wid ? w0tot : 0);
    cur[t] = ls;
    int n = n0 + t;
    if (n < n1){
      float dd = (float)v + 1.0f;
      dis[n]  = __fdiv_rn(1.0f, __fsqrt_rn(dd));
      offs[n] = gbeg + ls;
    }
    __syncthreads();
    for (int i = t; i < cnt_all; i += BNODES){
      ull k = ebuf[i];
      int pos = atomicAdd(&cur[(int)(k >> LD_SH)], 1);
      obuf[pos] = k;
    }
    __syncthreads();
    for (int i = ls + 1; i < ls + v; i++){
      ull k = obuf[i]; int j = i - 1;
      while (j >= ls && obuf[j] > k){ obuf[j + 1] = obuf[j]; j--; }
      obuf[j + 1] = k;
    }
    __syncthreads();
    for (int i = t; i < cnt_all; i += BNODES)
      csr[gbeg + i] = (int)(obuf[i] & SRC_MASK);
  } else {
    // statistically unreachable fallback (correct, slow)
    int n = n0 + t;
    int deg = 0;
    if (n < n1){
      for (int i = gbeg; i < gend; i++) if ((int)(staging[i] >> LD_SH) == t) deg++;
      float dd = (float)deg + 1.0f;
      dis[n] = __fdiv_rn(1.0f, __fsqrt_rn(dd));
    }
    cnt[t] = (n < n1) ? deg : 0;
    __syncthreads();
    if (n < n1){
      int ls = gbeg; for (int q = 0; q < t; q++) ls += cnt[q];
      offs[n] = ls;
      ull prev = 0;
      for (int o = 0; o < deg; o++){
        ull best = ~0ull;
        for (int i = gbeg; i < gend; i++){
          ull k = staging[i];
          if ((int)(k >> LD_SH) == t && (o == 0 || k > prev) && k < best) best = k;
        }
        csr[ls + o] = (int)(best & SRC_MASK); prev = best;
      }
    }
  }
  if (b == 0 && t == 0) offs[N] = E;
}

// ---------------- per-node matmul h = x @ W ----------------
template<int K>
__global__ void node_matmul(const float* __restrict__ xin, const float* __restrict__ W,
                            float* __restrict__ H, int N){
  __shared__ float Ws[K * 32];
  for (int i = threadIdx.x; i < K * 32; i += blockDim.x) Ws[i] = W[i];
  __syncthreads();
  int tid = blockIdx.x * blockDim.x + threadIdx.x;
  int n = tid >> 5, c = tid & 31;
  if (n >= N) return;
  const float* xr = xin + (size_t)n * K;
  float acc = 0.f;
  #pragma unroll
  for (int k = 0; k < K; k++) acc = fmaf(xr[k], Ws[k * 32 + c], acc);
  H[(size_t)n * 32 + c] = acc;
}

// ---------------- GCN aggregation: 8 lanes/node x float4, exact edge order ----------
__device__ __forceinline__ float4 acc_edge(float4 a, float4 h, float w){
  a.x = __fadd_rn(a.x, __fmul_rn(h.x, w));
  a.y = __fadd_rn(a.y, __fmul_rn(h.y, w));
  a.z = __fadd_rn(a.z, __fmul_rn(h.z, w));
  a.w = __fadd_rn(a.w, __fmul_rn(h.w, w));
  return a;
}

__global__ __launch_bounds__(256) void agg_kernel(const float* __restrict__ H,
                           const int* __restrict__ offsets,
                           const int* __restrict__ csr, const float* __restrict__ dis,
                           const float* __restrict__ bias, float* __restrict__ A,
                           float* __restrict__ keyout, int N){
  int tid = blockIdx.x * 256 + threadIdx.x;
  int n = tid >> 3, qw = tid & 7;         // 8 lanes per node, 4 channels per lane
  if (n >= N) return;
  const float4* __restrict__ H4 = (const float4*)H;
  float dn = dis[n];
  int s = offsets[n], e = offsets[n + 1];
  float4 acc = make_float4(0.f, 0.f, 0.f, 0.f);
  int i = s;
  for (; i + 4 <= e; i += 4){
    int s0 = csr[i], s1 = csr[i+1], s2 = csr[i+2], s3 = csr[i+3];
    float4 h0 = H4[(size_t)s0 * 8 + qw];
    float4 h1 = H4[(size_t)s1 * 8 + qw];
    float4 h2 = H4[(size_t)s2 * 8 + qw];
    float4 h3 = H4[(size_t)s3 * 8 + qw];
    float w0 = __fmul_rn(dis[s0], dn), w1 = __fmul_rn(dis[s1], dn);
    float w2 = __fmul_rn(dis[s2], dn), w3 = __fmul_rn(dis[s3], dn);
    acc = acc_edge(acc, h0, w0);          // per-channel order == reference order
    acc = acc_edge(acc, h1, w1);
    acc = acc_edge(acc, h2, w2);
    acc = acc_edge(acc, h3, w3);
  }
  for (; i < e; i++){
    int sr = csr[i];
    float w = __fmul_rn(dis[sr], dn);
    acc = acc_edge(acc, H4[(size_t)sr * 8 + qw], w);
  }
  float4 hn = H4[(size_t)n * 8 + qw];
  float sw = __fmul_rn(dn, dn);
  float4 bb = ((const float4*)bias)[qw];
  float4 v;
  v.x = fmaxf(__fadd_rn(__fadd_rn(acc.x, __fmul_rn(hn.x, sw)), bb.x), 0.f);
  v.y = fmaxf(__fadd_rn(__fadd_rn(acc.y, __fmul_rn(hn.y, sw)), bb.y), 0.f);
  v.z = fmaxf(__fadd_rn(__fadd_rn(acc.z, __fmul_rn(hn.z, sw)), bb.z), 0.f);
  v.w = fmaxf(__fadd_rn(__fadd_rn(acc.w, __fmul_rn(hn.w, sw)), bb.w), 0.f);
  ((float4*)A)[(size_t)n * 8 + qw] = v;
  if (keyout != nullptr && qw == 7) keyout[n] = v.w;   // channel 31 = sort key
}

// ---------------- graph boundaries (batch is sorted) ----------------
__global__ void gstarts_kernel(const int* __restrict__ batch, int* __restrict__ gstarts,
                               int N, int G){
  int g = blockIdx.x * blockDim.x + threadIdx.x;
  if (g > G) return;
  int lo = 0, hi = N;
  while (lo < hi){ int mid = (lo + hi) >> 1; if (batch[mid] < g) lo = mid + 1; else hi = mid; }
  gstarts[g] = lo;
}

// ------- fused head: sort-pool (top-30) -> conv1 -> conv2 -> dense1 -> dense2 ---------
__global__ __launch_bounds__(128) void head_kernel(
    const float* __restrict__ A, const float* __restrict__ keys,
    const int* __restrict__ gstarts,
    const float* __restrict__ cw1, const float* __restrict__ cb1,
    const float* __restrict__ cw2, const float* __restrict__ cb2,
    const float* __restrict__ lw1, const float* __restrict__ lb1,
    const float* __restrict__ lw2, const float* __restrict__ lb2,
    float* __restrict__ out){
  int g = blockIdx.x;
  int t = threadIdx.x;
  __shared__ float sin_[32 * 30];
  __shared__ float kbuf[KCAP];
  __shared__ int   sel[SORTK];
  __shared__ float c1[16 * 26];
  __shared__ float c2[32 * 22];
  __shared__ float d1[128];
  __shared__ float w1s[16 * 32 * 5];
  __shared__ float w2s[32 * 16 * 5];

  int s = gstarts[g], e = gstarts[g + 1];
  int c = e - s;
  bool fast = (c <= KCAP);

  for (int i = t; i < 960; i += 128)  sin_[i] = 0.f;
  for (int i = t; i < 2560; i += 128) w1s[i] = cw1[i];
  for (int i = t; i < 2560; i += 128) w2s[i] = cw2[i];
  if (fast) for (int i = t; i < c; i += 128) kbuf[i] = keys[s + i];  // coalesced
  __syncthreads();

  // stable top-30 rank: key desc, index asc
  for (int i = t; i < c; i += 128){
    float ki = fast ? kbuf[i] : keys[s + i];
    int rank = 0; bool ok = true;
    for (int j = 0; j < c; j++){
      float kj = fast ? kbuf[j] : keys[s + j];
      if (kj > ki || (kj == ki && j < i)){
        if (++rank >= SORTK){ ok = false; break; }
      }
    }
    if (ok) sel[rank] = i;
  }
  __syncthreads();

  // gather selected rows into conv layout sin_[ch*30+pos] (coalesced A reads)
  int kk = c < SORTK ? c : SORTK;
  for (int q = t; q < kk * 32; q += 128){
    int pos = q >> 5, ch = q & 31;
    sin_[ch * 30 + pos] = A[(size_t)(s + sel[pos]) * 32 + ch];
  }
  __syncthreads();

  // conv1: (32,30) -> (16,26)
  for (int q = t; q < 16 * 26; q += 128){
    int o = q / 26, tt = q % 26;
    float acc = cb1[o];
    const float* wo = &w1s[o * 160];
    for (int i = 0; i < 32; i++){
      const float* si = &sin_[i * 30 + tt];
      #pragma unroll
      for (int k = 0; k < 5; k++) acc = fmaf(si[k], wo[i * 5 + k], acc);
    }
    c1[q] = fmaxf(acc, 0.f);
  }
  __syncthreads();

  // conv2: (16,26) -> (32,22)
  for (int q = t; q < 32 * 22; q += 128){
    int o = q / 22, tt = q % 22;
    float acc = cb2[o];
    const float* wo = &w2s[o * 80];
    for (int i = 0; i < 16; i++){
      const float* si = &c1[i * 26 + tt];
      #pragma unroll
      for (int k = 0; k < 5; k++) acc = fmaf(si[k], wo[i * 5 + k], acc);
    }
    c2[q] = fmaxf(acc, 0.f);
  }
  __syncthreads();

  // dense1: 704 -> 128
  {
    float acc = lb1[t];
    for (int j = 0; j < 704; j++) acc = fmaf(c2[j], lw1[(size_t)j * 128 + t], acc);
    d1[t] = fmaxf(acc, 0.f);
  }
  __syncthreads();

  // dense2: 128 -> 1
  if (t == 0){
    float acc = lb2[0];
    for (int o = 0; o < 128; o++) acc = fmaf(d1[o], lw2[o], acc);
    out[g] = acc;
  }
}

// ---------------- launch ----------------
extern "C" void kernel_launch(void* const* d_in, const int* in_sizes, int n_in,
                              void* d_out, int out_size, void* d_ws, size_t ws_size,
                              hipStream_t stream){
  const float* x     = (const float*)d_in[0];
  const int*   ei    = (const int*)  d_in[1];
  const int*   batch = (const int*)  d_in[2];
  const float* W1  = (const float*)d_in[4];
  const float* b1  = (const float*)d_in[5];
  const float* W2  = (const float*)d_in[6];
  const float* b2  = (const float*)d_in[7];
  const float* W3  = (const float*)d_in[8];
  const float* b3  = (const float*)d_in[9];
  const float* cw1 = (const float*)d_in[10];
  const float* cb1 = (const float*)d_in[11];
  const float* cw2 = (const float*)d_in[12];
  const float* cb2 = (const float*)d_in[13];
  const float* lw1 = (const float*)d_in[14];
  const float* lb1 = (const float*)d_in[15];
  const float* lw2 = (const float*)d_in[16];
  const float* lb2 = (const float*)d_in[17];

  int N = in_sizes[0] / 9;
  int E = in_sizes[1] / 2;
  int G = out_size;
  const int* srcs = ei;
  const int* dsts = ei + E;
  int NB = ceil_div_i(N, BNODES);           // 1954 for N=250000
  int segsz = ceil_div_i(E, NSEG);

  char* base = (char*)d_ws;
  size_t off = 0;
  auto alloc = [&](size_t bytes) -> void* {
    off = (off + 255) & ~(size_t)255;
    void* r = base + off; off += bytes; return r;
  };
  float* dis    = (float*)alloc((size_t)N * 4);
  float* H      = (float*)alloc((size_t)N * 32 * 4);   // aliased as staging (E*8 <= N*128)
  float* A      = (float*)alloc((size_t)N * 32 * 4);
  float* keyarr = (float*)alloc((size_t)N * 4);
  int*   offs   = (int*)alloc((size_t)(N + 1) * 4);
  int*   csr    = (int*)alloc((size_t)E * 4);
  int*   gst    = (int*)alloc((size_t)(G + 1) * 4);
  int*   hist   = (int*)alloc((size_t)NSEG * NB * 4);
  int*   segoff = (int*)alloc((size_t)NSEG * NB * 4);
  int*   btot   = (int*)alloc((size_t)NB * 4);
  int*   bbase  = (int*)alloc((size_t)(NB + 1) * 4);
  ull*   staging = (ull*)H;   // alias: H written only after CSR build completes
  (void)ws_size; (void)n_in;

  // CSR build: histogram multisplit (no global atomics), src carried in payload
  hist_kernel<<<NSEG, 1024, 0, stream>>>(dsts, hist, E, NB, segsz);
  segscanA<<<ceil_div_i(NB, 256), 256, 0, stream>>>(hist, segoff, btot, NB, NSEG);
  segscanB<<<1, 1024, 0, stream>>>(btot, bbase, NB);
  scatter_kernel<<<NSEG, 1024, 0, stream>>>(dsts, srcs, segoff, bbase, staging, E, NB, segsz);
  bucket_sort_kernel<<<NB, BNODES, 0, stream>>>(bbase, staging, csr, offs, dis, N, NB, E);

  int ntm = ceil_div_i((long long)N * 32, 256);
  int nta = ceil_div_i((long long)N * 8, 256);
  node_matmul<9><<<ntm, 256, 0, stream>>>(x, W1, H, N);
  agg_kernel<<<nta, 256, 0, stream>>>(H, offs, csr, dis, b1, A, nullptr, N);
  node_matmul<32><<<ntm, 256, 0, stream>>>(A, W2, H, N);
  agg_kernel<<<nta, 256, 0, stream>>>(H, offs, csr, dis, b2, A, nullptr, N);
  node_matmul<32><<<ntm, 256, 0, stream>>>(A, W3, H, N);
  agg_kernel<<<nta, 256, 0, stream>>>(H, offs, csr, dis, b3, A, keyarr, N);

  gstarts_kernel<<<ceil_div_i(G + 1, 256), 256, 0, stream>>>(batch, gst, N, G);
  head_kernel<<<G, 128, 0, stream>>>(A, keyarr, gst, cw1, cb1, cw2, cb2,
                                     lw1, lb1, lw2, lb2, (float*)d_out);
}